// Round 2
// baseline (446.374 us; speedup 1.0000x reference)
//
#include <hip/hip_runtime.h>
#include <hip/hip_bf16.h>
#include <cstdint>
#include <cstddef>

// ---------------- types / helpers ----------------
typedef __attribute__((ext_vector_type(8))) __bf16 bf16x8;
typedef __attribute__((ext_vector_type(4))) float f32x4;
typedef __attribute__((ext_vector_type(8))) unsigned short us8;
typedef __attribute__((ext_vector_type(4))) unsigned short us4;

__device__ __forceinline__ unsigned short f2bf(float f){
  unsigned int u = __float_as_uint(f);
  u += 0x7fffu + ((u >> 16) & 1u);      // RNE
  return (unsigned short)(u >> 16);
}
__device__ __forceinline__ float bf2f(unsigned short h){
  return __uint_as_float(((unsigned int)h) << 16);
}
__device__ __forceinline__ bf16x8 ldbf8(const unsigned short* p){
  return __builtin_bit_cast(bf16x8, *(const us8*)p);
}

#define SCALE_E 0.35355339059327373f   // HEADS^-0.5

// ---------------- workspace layout (bytes) ----------------
// total required: ~119.9 MB
static const size_t OFF_XHI    = 0;               // u16 [16][256][4096]  (later: y1t)
static const size_t OFF_XLO    = 33554432;        // u16 [16][256][4096]  (later: Ot_hi)
static const size_t OFF_XTHI   = 67108864;        // u16 [16][4096][256]  (later: finalT)
static const size_t OFF_GPART  = 100663296;       // f32 [3][16][256][256]
static const size_t OFF_G      = 113246208;       // f32 [16][256][256]
static const size_t OFF_M      = 117440512;       // u16 [16][256][256]
static const size_t OFF_W1S    = 119537664;       // u16 [256][256]
static const size_t OFF_W2S    = 119668736;       // u16 [256][256]
static const size_t OFF_SIG    = 119799808;       // f32 [4]
static const size_t OFF_XSUM   = 119799824;       // f32 [16][256]
static const size_t OFF_ROWADD = 119816208;       // f32 [16][256]

// ---------------- K0: zero xsum ----------------
__global__ void k_zero(float* __restrict__ xsum){
  xsum[blockIdx.x * 256 + threadIdx.x] = 0.f;
}

// ---------------- K1: spectral-norm sigmas (2 blocks) ----------------
__global__ void k_sigma(const float* __restrict__ W1, const float* __restrict__ u1,
                        const float* __restrict__ W2, const float* __restrict__ u2,
                        float* __restrict__ sig){
  const float* W = blockIdx.x ? W2 : W1;
  const float* u = blockIdx.x ? u2 : u1;
  int t = threadIdx.x;
  __shared__ __align__(16) float red[256];
  __shared__ __align__(16) float vls[256];
  __shared__ __align__(16) float uls[256];
  uls[t] = u[t];
  __syncthreads();
  // t1 = W^T u   (thread t owns column t)
  float t1 = 0.f;
  for (int o = 0; o < 256; ++o) t1 += W[o*256 + t] * uls[o];
  red[t] = t1 * t1;
  __syncthreads();
  for (int s = 128; s > 0; s >>= 1){ if (t < s) red[t] += red[t+s]; __syncthreads(); }
  float nrm = sqrtf(red[0]);
  vls[t] = t1 / (nrm + 1e-12f);
  __syncthreads();
  // w = W v (thread t owns row t)
  float w = 0.f;
  const float4* wr4 = (const float4*)(W + t*256);
  for (int c4 = 0; c4 < 64; ++c4){
    float4 a = wr4[c4];
    float4 v = *(const float4*)&vls[c4*4];
    w += a.x*v.x + a.y*v.y + a.z*v.z + a.w*v.w;
  }
  __syncthreads();
  red[t] = w * w;
  __syncthreads();
  for (int s = 128; s > 0; s >>= 1){ if (t < s) red[t] += red[t+s]; __syncthreads(); }
  if (t == 0){
    float s2 = red[0];
    float sn = sqrtf(s2);
    sig[blockIdx.x] = s2 / (sn + 1e-12f);   // sigma = ||Wv||^2/(||Wv||+eps)
  }
}

// ---------------- K1b: W1/sigma1, W2/sigma2 -> bf16 ----------------
__global__ void k_wconv(const float* __restrict__ W1, const float* __restrict__ W2,
                        const float* __restrict__ sig,
                        unsigned short* __restrict__ W1s, unsigned short* __restrict__ W2s){
  int sel = blockIdx.x >> 6;
  const float* W = sel ? W2 : W1;
  unsigned short* o = sel ? W2s : W1s;
  float inv = 1.0f / sig[sel];
  int base = (blockIdx.x & 63) * 1024 + threadIdx.x * 4;
  float4 v = *(const float4*)&W[base];
  us4 r = { f2bf(v.x*inv), f2bf(v.y*inv), f2bf(v.z*inv), f2bf(v.w*inv) };
  *(us4*)&o[base] = r;
}

// ---------------- K2: x -> xhi/xlo ([c][n]) + xthi ([n][c]) + row sums ----------------
__global__ __launch_bounds__(256) void k_convert(const float* __restrict__ x,
    unsigned short* __restrict__ xhi, unsigned short* __restrict__ xlo,
    unsigned short* __restrict__ xthi, float* __restrict__ xsum){
  int b = blockIdx.z, c0 = blockIdx.y*64, n0 = blockIdx.x*64;
  int t = threadIdx.x, tn = t & 15, tc = t >> 4;
  __shared__ __align__(16) unsigned short hs[64][68];
  __shared__ __align__(16) float ps[64][17];
  #pragma unroll
  for (int rr = 0; rr < 4; ++rr){
    int cl = rr*16 + tc;
    size_t gro = ((size_t)(b*256 + c0 + cl))*4096 + n0 + tn*4;
    float4 v = *(const float4*)&x[gro];
    unsigned short h0=f2bf(v.x), h1=f2bf(v.y), h2=f2bf(v.z), h3=f2bf(v.w);
    us4 hv = {h0,h1,h2,h3};
    us4 lv = { f2bf(v.x - bf2f(h0)), f2bf(v.y - bf2f(h1)),
               f2bf(v.z - bf2f(h2)), f2bf(v.w - bf2f(h3)) };
    *(us4*)&xhi[gro] = hv;
    *(us4*)&xlo[gro] = lv;
    *(us4*)&hs[cl][tn*4] = hv;
    ps[cl][tn] = v.x + v.y + v.z + v.w;
  }
  __syncthreads();
  #pragma unroll
  for (int rr = 0; rr < 4; ++rr){
    int nl = rr*16 + tc;
    int cl4 = tn*4;
    us4 w = { hs[cl4+0][nl], hs[cl4+1][nl], hs[cl4+2][nl], hs[cl4+3][nl] };
    *(us4*)&xthi[((size_t)(b*4096 + n0 + nl))*256 + c0 + cl4] = w;
  }
  if (t < 64){
    float s = 0.f;
    #pragma unroll
    for (int k = 0; k < 16; ++k) s += ps[t][k];
    atomicAdd(&xsum[b*256 + c0 + t], s);
  }
}

// ---------------- K3: Gram G_b = X X^T in split-bf16 MFMA ----------------
__global__ __launch_bounds__(256) void k_gram(const unsigned short* __restrict__ xhi,
    const unsigned short* __restrict__ xlo, float* __restrict__ G, float* __restrict__ Gp){
  int b = blockIdx.z;
  int tr = (blockIdx.y >> 1) * 128, tc = (blockIdx.y & 1) * 128;
  int kc = blockIdx.x * 1024;
  int t = threadIdx.x;
  __shared__ __align__(16) unsigned short Ah[128*40], Al[128*40], Bh[128*40], Bl[128*40];
  f32x4 acc[4][4];
  #pragma unroll
  for (int i = 0; i < 4; ++i)
    #pragma unroll
    for (int j = 0; j < 4; ++j) acc[i][j] = (f32x4){0.f,0.f,0.f,0.f};
  int srow = t >> 1, skh = (t & 1) * 16;
  int l = t & 63, wv = t >> 6;
  int wr = (wv >> 1) * 64, wc = (wv & 1) * 64;
  int lr = l & 15, lg = l >> 4;
  size_t bb = (size_t)b * 256 * 4096;
  for (int kk = kc; kk < kc + 1024; kk += 32){
    __syncthreads();
    size_t ga = bb + (size_t)(tr + srow)*4096 + kk + skh;
    size_t gb = bb + (size_t)(tc + srow)*4096 + kk + skh;
    *(us8*)&Ah[srow*40 + skh]     = *(const us8*)&xhi[ga];
    *(us8*)&Ah[srow*40 + skh + 8] = *(const us8*)&xhi[ga + 8];
    *(us8*)&Al[srow*40 + skh]     = *(const us8*)&xlo[ga];
    *(us8*)&Al[srow*40 + skh + 8] = *(const us8*)&xlo[ga + 8];
    *(us8*)&Bh[srow*40 + skh]     = *(const us8*)&xhi[gb];
    *(us8*)&Bh[srow*40 + skh + 8] = *(const us8*)&xhi[gb + 8];
    *(us8*)&Bl[srow*40 + skh]     = *(const us8*)&xlo[gb];
    *(us8*)&Bl[srow*40 + skh + 8] = *(const us8*)&xlo[gb + 8];
    __syncthreads();
    bf16x8 ah[4], alv[4], bh[4], blv[4];
    #pragma unroll
    for (int i = 0; i < 4; ++i){
      ah[i]  = ldbf8(&Ah[(wr + i*16 + lr)*40 + lg*8]);
      alv[i] = ldbf8(&Al[(wr + i*16 + lr)*40 + lg*8]);
      bh[i]  = ldbf8(&Bh[(wc + i*16 + lr)*40 + lg*8]);
      blv[i] = ldbf8(&Bl[(wc + i*16 + lr)*40 + lg*8]);
    }
    #pragma unroll
    for (int i = 0; i < 4; ++i)
      #pragma unroll
      for (int j = 0; j < 4; ++j){
        acc[i][j] = __builtin_amdgcn_mfma_f32_16x16x32_bf16(ah[i],  bh[j],  acc[i][j], 0,0,0);
        acc[i][j] = __builtin_amdgcn_mfma_f32_16x16x32_bf16(ah[i],  blv[j], acc[i][j], 0,0,0);
        acc[i][j] = __builtin_amdgcn_mfma_f32_16x16x32_bf16(alv[i], bh[j],  acc[i][j], 0,0,0);
      }
  }
  float* dst = (blockIdx.x == 0) ? (G + (size_t)b*65536)
                                 : (Gp + ((size_t)(blockIdx.x - 1)*16 + b)*65536);
  #pragma unroll
  for (int i = 0; i < 4; ++i)
    #pragma unroll
    for (int j = 0; j < 4; ++j)
      #pragma unroll
      for (int r = 0; r < 4; ++r){
        int row = tr + wr + i*16 + lg*4 + r;
        int col = tc + wc + j*16 + lr;
        dst[row*256 + col] = acc[i][j][r];
      }
}

// ---------------- K3b: G += 3 partials ----------------
__global__ void k_gred(float* __restrict__ G, const float* __restrict__ Gp){
  size_t idx = ((size_t)blockIdx.x * 256 + threadIdx.x) * 4;
  float4 g  = *(float4*)&G[idx];
  float4 p0 = *(const float4*)&Gp[idx];
  float4 p1 = *(const float4*)&Gp[idx + 1048576];
  float4 p2 = *(const float4*)&Gp[idx + 2097152];
  g.x += p0.x + p1.x + p2.x;  g.y += p0.y + p1.y + p2.y;
  g.z += p0.z + p1.z + p2.z;  g.w += p0.w + p1.w + p2.w;
  *(float4*)&G[idx] = g;
}

// ---------------- K4: energy = s*Qh*G*Kh^T, softmax, M = gamma*attn@Wv ----------------
__global__ __launch_bounds__(256) void k_attn(const float* __restrict__ G,
    const float* __restrict__ Wq, const float* __restrict__ bq,
    const float* __restrict__ Wk, const float* __restrict__ bk,
    const float* __restrict__ Wv, const float* __restrict__ bv,
    const float* __restrict__ gptr, const float* __restrict__ xsum,
    unsigned short* __restrict__ Mw, float* __restrict__ rowadd,
    float* __restrict__ attn_out){
  int bh = blockIdx.x, b = bh >> 3, h = bh & 7;
  int t = threadIdx.x;
  __shared__ __align__(16) float Qh[32*256];
  __shared__ __align__(16) float Tl[32*260];
  __shared__ __align__(16) float El[32*36];
  __shared__ __align__(16) float Aw[32*36];
  __shared__ float qsv[32], ksv[32];
  // stage Qh (= Wq rows of this head), coalesced float4
  {
    const float4* wq4 = (const float4*)(Wq + (size_t)h*32*256);
    float4* qh4 = (float4*)Qh;
    #pragma unroll
    for (int it = 0; it < 8; ++it) qh4[it*256 + t] = wq4[it*256 + t];
  }
  __syncthreads();
  // T = Qh * G   (thread t owns G column t; use symmetry: G[:,t] == G[t,:])
  float Tr[32];
  #pragma unroll
  for (int i = 0; i < 32; ++i) Tr[i] = 0.f;
  const float* Grow = G + ((size_t)b*256 + t)*256;
  for (int c4 = 0; c4 < 64; ++c4){
    float4 g4 = *(const float4*)&Grow[c4*4];
    #pragma unroll
    for (int i = 0; i < 32; ++i){
      float4 q4 = *(const float4*)&Qh[i*256 + c4*4];
      Tr[i] += q4.x*g4.x + q4.y*g4.y + q4.z*g4.z + q4.w*g4.w;
    }
  }
  #pragma unroll
  for (int i = 0; i < 32; ++i) Tl[i*260 + t] = Tr[i];
  // bias-correction row sums (zero in this benchmark, kept for correctness)
  if (t < 32){
    float s = 0.f; const float* qr = Qh + t*256; const float* xs = xsum + b*256;
    for (int c = 0; c < 256; ++c) s += qr[c]*xs[c];
    qsv[t] = s;
  } else if (t < 64){
    int j = t - 32; float s = 0.f;
    const float* kr = Wk + (size_t)(h*32 + j)*256; const float* xs = xsum + b*256;
    for (int c = 0; c < 256; ++c) s += kr[c]*xs[c];
    ksv[j] = s;
  }
  __syncthreads();
  // E[i][j] = scale * (T_i . Kh_j + bias terms)
  {
    int i = t >> 3, jb = (t & 7) * 4;
    float e0=0.f, e1=0.f, e2=0.f, e3=0.f;
    const float* Ti = Tl + i*260;
    const float* k0 = Wk + (size_t)(h*32 + jb + 0)*256;
    const float* k1 = Wk + (size_t)(h*32 + jb + 1)*256;
    const float* k2 = Wk + (size_t)(h*32 + jb + 2)*256;
    const float* k3 = Wk + (size_t)(h*32 + jb + 3)*256;
    for (int c4 = 0; c4 < 64; ++c4){
      float4 tv = *(const float4*)&Ti[c4*4];
      float4 a0 = *(const float4*)&k0[c4*4];
      float4 a1 = *(const float4*)&k1[c4*4];
      float4 a2 = *(const float4*)&k2[c4*4];
      float4 a3 = *(const float4*)&k3[c4*4];
      e0 += tv.x*a0.x + tv.y*a0.y + tv.z*a0.z + tv.w*a0.w;
      e1 += tv.x*a1.x + tv.y*a1.y + tv.z*a1.z + tv.w*a1.w;
      e2 += tv.x*a2.x + tv.y*a2.y + tv.z*a2.z + tv.w*a2.w;
      e3 += tv.x*a3.x + tv.y*a3.y + tv.z*a3.z + tv.w*a3.w;
    }
    float bqi = bq[h*32 + i];
    float e[4] = {e0,e1,e2,e3};
    #pragma unroll
    for (int jj = 0; jj < 4; ++jj){
      float bkj = bk[h*32 + jb + jj];
      El[i*36 + jb + jj] = SCALE_E * (e[jj] + bqi*ksv[jb+jj] + bkj*qsv[i] + 4096.f*bqi*bkj);
    }
  }
  __syncthreads();
  // softmax rows + attn output
  if (t < 32){
    float m = -1e30f;
    #pragma unroll
    for (int j = 0; j < 32; ++j) m = fmaxf(m, El[t*36 + j]);
    float ex[32]; float s = 0.f;
    #pragma unroll
    for (int j = 0; j < 32; ++j){ ex[j] = expf(El[t*36 + j] - m); s += ex[j]; }
    float inv = 1.f / s;
    float* ao = attn_out + (((size_t)(b*8 + h))*32 + t)*32;
    #pragma unroll
    for (int j = 0; j < 32; ++j){ float a = ex[j]*inv; Aw[t*36 + j] = a; ao[j] = a; }
  }
  __syncthreads();
  float gamma = gptr[0];
  // M[o=h*32+i][c=t] = gamma * sum_j attn[i][j] * Wv[h*32+j][c]
  float mr[32];
  #pragma unroll
  for (int i = 0; i < 32; ++i) mr[i] = 0.f;
  for (int j = 0; j < 32; ++j){
    float wvv = Wv[(size_t)(h*32 + j)*256 + t];
    #pragma unroll
    for (int i = 0; i < 32; ++i) mr[i] += Aw[i*36 + j] * wvv;
  }
  unsigned short* Mrow = Mw + ((size_t)b*256 + h*32)*256 + t;
  #pragma unroll
  for (int i = 0; i < 32; ++i) Mrow[i*256] = f2bf(gamma * mr[i]);
  if (t < 32){
    float s = 0.f;
    #pragma unroll
    for (int j = 0; j < 32; ++j) s += Aw[t*36 + j] * bv[h*32 + j];
    rowadd[b*256 + h*32 + t] = gamma * s;
  }
}

// ---------------- K5/K6/K7: transposed-world GEMM, C^T = A(nxk) * B(256x256)^T ----------------
// MODE 0: O^T = X^T M^T; epilogue O = acc + x + rowadd -> osc(f32) + outb(bf16)
// MODE 1: y1^T = O^T W1s^T; epilogue lrelu(acc + b1) -> outb(bf16)
// MODE 2: y2^T = y1^T W2s^T; epilogue final = osc + beta*(acc + b2) -> outb(bf16)
template<int MODE>
__global__ __launch_bounds__(256) void k_gemm(const unsigned short* __restrict__ Aall,
    const unsigned short* __restrict__ Bmat, const unsigned short* __restrict__ xthi,
    const float* __restrict__ rowadd, const float* __restrict__ bias,
    const float* __restrict__ betap, float* __restrict__ osc,
    unsigned short* __restrict__ outb){
  int b = blockIdx.z;
  int n0 = blockIdx.x * 128, o0 = blockIdx.y * 128;
  int t = threadIdx.x;
  __shared__ __align__(16) unsigned short Als[128*40], Bls[128*40];
  f32x4 acc[4][4];
  #pragma unroll
  for (int i = 0; i < 4; ++i)
    #pragma unroll
    for (int j = 0; j < 4; ++j) acc[i][j] = (f32x4){0.f,0.f,0.f,0.f};
  const unsigned short* A  = Aall + (size_t)b * 1048576;
  const unsigned short* Bp = (MODE == 0) ? (Bmat + (size_t)b * 65536) : Bmat;
  int srow = t >> 1, skh = (t & 1) * 16;
  int l = t & 63, wv = t >> 6;
  int wr = (wv >> 1) * 64, wc = (wv & 1) * 64;
  int lr = l & 15, lg = l >> 4;
  for (int kk = 0; kk < 256; kk += 32){
    __syncthreads();
    const unsigned short* ga = A  + (size_t)(n0 + srow)*256 + kk + skh;
    const unsigned short* gb = Bp + (size_t)(o0 + srow)*256 + kk + skh;
    *(us8*)&Als[srow*40 + skh]     = *(const us8*)ga;
    *(us8*)&Als[srow*40 + skh + 8] = *(const us8*)(ga + 8);
    *(us8*)&Bls[srow*40 + skh]     = *(const us8*)gb;
    *(us8*)&Bls[srow*40 + skh + 8] = *(const us8*)(gb + 8);
    __syncthreads();
    bf16x8 af[4], bfv[4];
    #pragma unroll
    for (int i = 0; i < 4; ++i) af[i]  = ldbf8(&Als[(wr + i*16 + lr)*40 + lg*8]);
    #pragma unroll
    for (int j = 0; j < 4; ++j) bfv[j] = ldbf8(&Bls[(wc + j*16 + lr)*40 + lg*8]);
    #pragma unroll
    for (int i = 0; i < 4; ++i)
      #pragma unroll
      for (int j = 0; j < 4; ++j)
        acc[i][j] = __builtin_amdgcn_mfma_f32_16x16x32_bf16(af[i], bfv[j], acc[i][j], 0,0,0);
  }
  float beta = (MODE == 2) ? betap[0] : 0.f;
  #pragma unroll
  for (int j = 0; j < 4; ++j){
    int oc = o0 + wc + j*16 + lr;
    float bvl = (MODE == 0) ? rowadd[b*256 + oc] : bias[oc];
    #pragma unroll
    for (int i = 0; i < 4; ++i){
      #pragma unroll
      for (int r = 0; r < 4; ++r){
        int n = n0 + wr + i*16 + lg*4 + r;
        size_t off = ((size_t)b*4096 + n)*256 + oc;
        float v = acc[i][j][r];
        if (MODE == 0){
          v += bf2f(xthi[off]) + bvl;
          osc[off] = v;
          outb[off] = f2bf(v);
        } else if (MODE == 1){
          v += bvl;
          v = (v > 0.f) ? v : 0.1f * v;
          outb[off] = f2bf(v);
        } else {
          v = osc[off] + beta * (v + bvl);
          outb[off] = f2bf(v);
        }
      }
    }
  }
}

// ---------------- K8: final^T [n][c] bf16 -> out [c][n] f32 ----------------
__global__ __launch_bounds__(256) void k_tpose(const unsigned short* __restrict__ fin,
                                               float* __restrict__ out){
  int b = blockIdx.z, c0 = blockIdx.y*64, n0 = blockIdx.x*64;
  int t = threadIdx.x, tn = t & 15, tc = t >> 4;
  __shared__ __align__(16) unsigned short ts[64][68];
  #pragma unroll
  for (int rr = 0; rr < 4; ++rr){
    int nl = rr*16 + tc;
    us4 v = *(const us4*)&fin[((size_t)(b*4096 + n0 + nl))*256 + c0 + tn*4];
    *(us4*)&ts[nl][tn*4] = v;
  }
  __syncthreads();
  #pragma unroll
  for (int rr = 0; rr < 4; ++rr){
    int cl = rr*16 + tc;
    int nl4 = tn*4;
    float4 v = { bf2f(ts[nl4+0][cl]), bf2f(ts[nl4+1][cl]),
                 bf2f(ts[nl4+2][cl]), bf2f(ts[nl4+3][cl]) };
    *(float4*)&out[((size_t)(b*256 + c0 + cl))*4096 + n0 + nl4] = v;
  }
}

// ---------------- launch ----------------
extern "C" void kernel_launch(void* const* d_in, const int* in_sizes, int n_in,
                              void* d_out, int out_size, void* d_ws, size_t ws_size,
                              hipStream_t stream){
  const float* x    = (const float*)d_in[0];
  const float* Wq   = (const float*)d_in[1];
  const float* bq   = (const float*)d_in[2];
  const float* Wk   = (const float*)d_in[3];
  const float* bk   = (const float*)d_in[4];
  const float* Wv   = (const float*)d_in[5];
  const float* bv   = (const float*)d_in[6];
  const float* gamma= (const float*)d_in[7];
  const float* beta = (const float*)d_in[8];
  const float* W1   = (const float*)d_in[9];
  const float* b1   = (const float*)d_in[10];
  const float* u1   = (const float*)d_in[11];
  const float* W2   = (const float*)d_in[12];
  const float* b2   = (const float*)d_in[13];
  const float* u2   = (const float*)d_in[14];

  char* ws = (char*)d_ws;
  unsigned short* xhi   = (unsigned short*)(ws + OFF_XHI);
  unsigned short* xlo   = (unsigned short*)(ws + OFF_XLO);
  unsigned short* xthi  = (unsigned short*)(ws + OFF_XTHI);
  float*          Gp    = (float*)(ws + OFF_GPART);
  float*          G     = (float*)(ws + OFF_G);
  unsigned short* Mw    = (unsigned short*)(ws + OFF_M);
  unsigned short* W1s   = (unsigned short*)(ws + OFF_W1S);
  unsigned short* W2s   = (unsigned short*)(ws + OFF_W2S);
  float*          sig   = (float*)(ws + OFF_SIG);
  float*          xsum  = (float*)(ws + OFF_XSUM);
  float*          rowadd= (float*)(ws + OFF_ROWADD);
  // aliases (lifetimes disjoint):
  unsigned short* othi  = xlo;    // O^T bf16, written K5, read K6
  unsigned short* y1t   = xhi;    // y1^T bf16, written K6, read K7
  unsigned short* finT  = xthi;   // final^T bf16, written K7, read K8

  float* outF  = (float*)d_out;
  float* attnO = outF + 16777216;   // second output (attn)
  float* osc   = outF;              // O^T f32 scratch inside d_out[0:16M)

  k_zero<<<dim3(16), dim3(256), 0, stream>>>(xsum);
  k_sigma<<<dim3(2), dim3(256), 0, stream>>>(W1, u1, W2, u2, sig);
  k_wconv<<<dim3(128), dim3(256), 0, stream>>>(W1, W2, sig, W1s, W2s);
  k_convert<<<dim3(64,4,16), dim3(256), 0, stream>>>(x, xhi, xlo, xthi, xsum);
  k_gram<<<dim3(4,4,16), dim3(256), 0, stream>>>(xhi, xlo, G, Gp);
  k_gred<<<dim3(1024), dim3(256), 0, stream>>>(G, Gp);
  k_attn<<<dim3(128), dim3(256), 0, stream>>>(G, Wq, bq, Wk, bk, Wv, bv,
                                              gamma, xsum, Mw, rowadd, attnO);
  k_gemm<0><<<dim3(32,2,16), dim3(256), 0, stream>>>(xthi, Mw, xthi, rowadd, b1, beta, osc, othi);
  k_gemm<1><<<dim3(32,2,16), dim3(256), 0, stream>>>(othi, W1s, xthi, rowadd, b1, beta, osc, y1t);
  k_gemm<2><<<dim3(32,2,16), dim3(256), 0, stream>>>(y1t, W2s, xthi, rowadd, b2, beta, osc, finT);
  k_tpose<<<dim3(64,4,16), dim3(256), 0, stream>>>(finT, outF);
}

// Round 3
// 424.545 us; speedup vs baseline: 1.0514x; 1.0514x over previous
//
#include <hip/hip_runtime.h>
#include <hip/hip_bf16.h>
#include <cstdint>
#include <cstddef>

// ---------------- types / helpers ----------------
typedef __attribute__((ext_vector_type(8))) __bf16 bf16x8;
typedef __attribute__((ext_vector_type(4))) float f32x4;
typedef __attribute__((ext_vector_type(8))) unsigned short us8;
typedef __attribute__((ext_vector_type(4))) unsigned short us4;

__device__ __forceinline__ unsigned short f2bf(float f){
  unsigned int u = __float_as_uint(f);
  u += 0x7fffu + ((u >> 16) & 1u);      // RNE
  return (unsigned short)(u >> 16);
}
__device__ __forceinline__ float bf2f(unsigned short h){
  return __uint_as_float(((unsigned int)h) << 16);
}
__device__ __forceinline__ bf16x8 ldbf8(const unsigned short* p){
  return __builtin_bit_cast(bf16x8, *(const us8*)p);
}
// split 16 consecutive f32 into bf16 hi/lo halves (for LDS staging)
__device__ __forceinline__ void split16(const float* __restrict__ g,
                                        unsigned short* __restrict__ hs,
                                        unsigned short* __restrict__ ls){
  #pragma unroll
  for (int q = 0; q < 4; ++q){
    float4 v = *(const float4*)(g + q*4);
    unsigned short h0=f2bf(v.x), h1=f2bf(v.y), h2=f2bf(v.z), h3=f2bf(v.w);
    us4 hv = {h0,h1,h2,h3};
    us4 lv = { f2bf(v.x - bf2f(h0)), f2bf(v.y - bf2f(h1)),
               f2bf(v.z - bf2f(h2)), f2bf(v.w - bf2f(h3)) };
    *(us4*)(hs + q*4) = hv;
    *(us4*)(ls + q*4) = lv;
  }
}

#define SCALE_E 0.35355339059327373f   // HEADS^-0.5

// ---------------- workspace layout (bytes) ----------------
static const size_t OFF_XHI    = 0;               // u16 [16][256][4096]  (later: y1t)
static const size_t OFF_XLO    = 33554432;        // u16 [16][256][4096]  (later: Ghi/Glo, then othi)
static const size_t OFF_XTHI   = 67108864;        // u16 [16][4096][256]  (later: finalT)
static const size_t OFF_GPART  = 100663296;       // f32 [3][16][256][256] (later: Phi/Plo/Ef)
static const size_t OFF_G      = 113246208;       // f32 [16][256][256]  (gram partial 0)
static const size_t OFF_M      = 117440512;       // u16 [16][256][256]
static const size_t OFF_W1S    = 119537664;       // u16 [256][256]
static const size_t OFF_W2S    = 119668736;       // u16 [256][256]
static const size_t OFF_SIG    = 119799808;       // f32 [4]
static const size_t OFF_XSUM   = 119799824;       // f32 [16][256]
static const size_t OFF_ROWADD = 119816208;       // f32 [16][256]

// ---------------- K0: zero xsum ----------------
__global__ void k_zero(float* __restrict__ xsum){
  xsum[blockIdx.x * 256 + threadIdx.x] = 0.f;
}

// ---------------- K1: spectral-norm sigmas (2 blocks) ----------------
__global__ void k_sigma(const float* __restrict__ W1, const float* __restrict__ u1,
                        const float* __restrict__ W2, const float* __restrict__ u2,
                        float* __restrict__ sig){
  const float* W = blockIdx.x ? W2 : W1;
  const float* u = blockIdx.x ? u2 : u1;
  int t = threadIdx.x;
  __shared__ __align__(16) float red[256];
  __shared__ __align__(16) float vls[256];
  __shared__ __align__(16) float uls[256];
  uls[t] = u[t];
  __syncthreads();
  float t1 = 0.f;
  for (int o = 0; o < 256; ++o) t1 += W[o*256 + t] * uls[o];
  red[t] = t1 * t1;
  __syncthreads();
  for (int s = 128; s > 0; s >>= 1){ if (t < s) red[t] += red[t+s]; __syncthreads(); }
  float nrm = sqrtf(red[0]);
  vls[t] = t1 / (nrm + 1e-12f);
  __syncthreads();
  float w = 0.f;
  const float4* wr4 = (const float4*)(W + t*256);
  for (int c4 = 0; c4 < 64; ++c4){
    float4 a = wr4[c4];
    float4 v = *(const float4*)&vls[c4*4];
    w += a.x*v.x + a.y*v.y + a.z*v.z + a.w*v.w;
  }
  __syncthreads();
  red[t] = w * w;
  __syncthreads();
  for (int s = 128; s > 0; s >>= 1){ if (t < s) red[t] += red[t+s]; __syncthreads(); }
  if (t == 0){
    float s2 = red[0];
    float sn = sqrtf(s2);
    sig[blockIdx.x] = s2 / (sn + 1e-12f);
  }
}

// ---------------- K1b: W1/sigma1, W2/sigma2 -> bf16 ----------------
__global__ void k_wconv(const float* __restrict__ W1, const float* __restrict__ W2,
                        const float* __restrict__ sig,
                        unsigned short* __restrict__ W1s, unsigned short* __restrict__ W2s){
  int sel = blockIdx.x >> 6;
  const float* W = sel ? W2 : W1;
  unsigned short* o = sel ? W2s : W1s;
  float inv = 1.0f / sig[sel];
  int base = (blockIdx.x & 63) * 1024 + threadIdx.x * 4;
  float4 v = *(const float4*)&W[base];
  us4 r = { f2bf(v.x*inv), f2bf(v.y*inv), f2bf(v.z*inv), f2bf(v.w*inv) };
  *(us4*)&o[base] = r;
}

// ---------------- K2: x -> xhi/xlo ([c][n]) + xthi ([n][c]) + row sums ----------------
__global__ __launch_bounds__(256) void k_convert(const float* __restrict__ x,
    unsigned short* __restrict__ xhi, unsigned short* __restrict__ xlo,
    unsigned short* __restrict__ xthi, float* __restrict__ xsum){
  int b = blockIdx.z, c0 = blockIdx.y*64, n0 = blockIdx.x*64;
  int t = threadIdx.x, tn = t & 15, tc = t >> 4;
  __shared__ __align__(16) unsigned short hs[64][68];
  __shared__ __align__(16) float ps[64][17];
  #pragma unroll
  for (int rr = 0; rr < 4; ++rr){
    int cl = rr*16 + tc;
    size_t gro = ((size_t)(b*256 + c0 + cl))*4096 + n0 + tn*4;
    float4 v = *(const float4*)&x[gro];
    unsigned short h0=f2bf(v.x), h1=f2bf(v.y), h2=f2bf(v.z), h3=f2bf(v.w);
    us4 hv = {h0,h1,h2,h3};
    us4 lv = { f2bf(v.x - bf2f(h0)), f2bf(v.y - bf2f(h1)),
               f2bf(v.z - bf2f(h2)), f2bf(v.w - bf2f(h3)) };
    *(us4*)&xhi[gro] = hv;
    *(us4*)&xlo[gro] = lv;
    *(us4*)&hs[cl][tn*4] = hv;
    ps[cl][tn] = v.x + v.y + v.z + v.w;
  }
  __syncthreads();
  #pragma unroll
  for (int rr = 0; rr < 4; ++rr){
    int nl = rr*16 + tc;
    int cl4 = tn*4;
    us4 w = { hs[cl4+0][nl], hs[cl4+1][nl], hs[cl4+2][nl], hs[cl4+3][nl] };
    *(us4*)&xthi[((size_t)(b*4096 + n0 + nl))*256 + c0 + cl4] = w;
  }
  if (t < 64){
    float s = 0.f;
    #pragma unroll
    for (int k = 0; k < 16; ++k) s += ps[t][k];
    atomicAdd(&xsum[b*256 + c0 + t], s);
  }
}

// ---------------- K3: Gram G_b = X X^T in split-bf16 MFMA ----------------
__global__ __launch_bounds__(256) void k_gram(const unsigned short* __restrict__ xhi,
    const unsigned short* __restrict__ xlo, float* __restrict__ G, float* __restrict__ Gp){
  int b = blockIdx.z;
  int tr = (blockIdx.y >> 1) * 128, tc = (blockIdx.y & 1) * 128;
  int kc = blockIdx.x * 1024;
  int t = threadIdx.x;
  __shared__ __align__(16) unsigned short Ah[128*40], Al[128*40], Bh[128*40], Bl[128*40];
  f32x4 acc[4][4];
  #pragma unroll
  for (int i = 0; i < 4; ++i)
    #pragma unroll
    for (int j = 0; j < 4; ++j) acc[i][j] = (f32x4){0.f,0.f,0.f,0.f};
  int srow = t >> 1, skh = (t & 1) * 16;
  int l = t & 63, wv = t >> 6;
  int wr = (wv >> 1) * 64, wc = (wv & 1) * 64;
  int lr = l & 15, lg = l >> 4;
  size_t bb = (size_t)b * 256 * 4096;
  for (int kk = kc; kk < kc + 1024; kk += 32){
    __syncthreads();
    size_t ga = bb + (size_t)(tr + srow)*4096 + kk + skh;
    size_t gb = bb + (size_t)(tc + srow)*4096 + kk + skh;
    *(us8*)&Ah[srow*40 + skh]     = *(const us8*)&xhi[ga];
    *(us8*)&Ah[srow*40 + skh + 8] = *(const us8*)&xhi[ga + 8];
    *(us8*)&Al[srow*40 + skh]     = *(const us8*)&xlo[ga];
    *(us8*)&Al[srow*40 + skh + 8] = *(const us8*)&xlo[ga + 8];
    *(us8*)&Bh[srow*40 + skh]     = *(const us8*)&xhi[gb];
    *(us8*)&Bh[srow*40 + skh + 8] = *(const us8*)&xhi[gb + 8];
    *(us8*)&Bl[srow*40 + skh]     = *(const us8*)&xlo[gb];
    *(us8*)&Bl[srow*40 + skh + 8] = *(const us8*)&xlo[gb + 8];
    __syncthreads();
    bf16x8 ah[4], alv[4], bh[4], blv[4];
    #pragma unroll
    for (int i = 0; i < 4; ++i){
      ah[i]  = ldbf8(&Ah[(wr + i*16 + lr)*40 + lg*8]);
      alv[i] = ldbf8(&Al[(wr + i*16 + lr)*40 + lg*8]);
      bh[i]  = ldbf8(&Bh[(wc + i*16 + lr)*40 + lg*8]);
      blv[i] = ldbf8(&Bl[(wc + i*16 + lr)*40 + lg*8]);
    }
    #pragma unroll
    for (int i = 0; i < 4; ++i)
      #pragma unroll
      for (int j = 0; j < 4; ++j){
        acc[i][j] = __builtin_amdgcn_mfma_f32_16x16x32_bf16(ah[i],  bh[j],  acc[i][j], 0,0,0);
        acc[i][j] = __builtin_amdgcn_mfma_f32_16x16x32_bf16(ah[i],  blv[j], acc[i][j], 0,0,0);
        acc[i][j] = __builtin_amdgcn_mfma_f32_16x16x32_bf16(alv[i], bh[j],  acc[i][j], 0,0,0);
      }
  }
  float* dst = (blockIdx.x == 0) ? (G + (size_t)b*65536)
                                 : (Gp + ((size_t)(blockIdx.x - 1)*16 + b)*65536);
  #pragma unroll
  for (int i = 0; i < 4; ++i)
    #pragma unroll
    for (int j = 0; j < 4; ++j)
      #pragma unroll
      for (int r = 0; r < 4; ++r){
        int row = tr + wr + i*16 + lg*4 + r;
        int col = tc + wc + j*16 + lr;
        dst[row*256 + col] = acc[i][j][r];
      }
}

// ---------------- K3b: G = sum of 4 partials -> bf16 hi/lo ----------------
__global__ void k_gred(const float* __restrict__ G0, const float* __restrict__ Gp,
                       unsigned short* __restrict__ Ghi, unsigned short* __restrict__ Glo){
  size_t idx = ((size_t)blockIdx.x * 256 + threadIdx.x) * 4;
  float4 g  = *(const float4*)&G0[idx];
  float4 p0 = *(const float4*)&Gp[idx];
  float4 p1 = *(const float4*)&Gp[idx + 1048576];
  float4 p2 = *(const float4*)&Gp[idx + 2097152];
  float s0 = g.x + p0.x + p1.x + p2.x;
  float s1 = g.y + p0.y + p1.y + p2.y;
  float s2 = g.z + p0.z + p1.z + p2.z;
  float s3 = g.w + p0.w + p1.w + p2.w;
  unsigned short h0=f2bf(s0), h1=f2bf(s1), h2=f2bf(s2), h3=f2bf(s3);
  us4 hv = {h0,h1,h2,h3};
  us4 lv = { f2bf(s0 - bf2f(h0)), f2bf(s1 - bf2f(h1)),
             f2bf(s2 - bf2f(h2)), f2bf(s3 - bf2f(h3)) };
  *(us4*)&Ghi[idx] = hv;
  *(us4*)&Glo[idx] = lv;
}

// ---------------- K4a: P_b = Wq * G_b (split-bf16, 3-term), out hi/lo bf16 --------
__global__ __launch_bounds__(256) void k_qg(const float* __restrict__ Wq,
    const unsigned short* __restrict__ Ghi, const unsigned short* __restrict__ Glo,
    unsigned short* __restrict__ Phi, unsigned short* __restrict__ Plo){
  int b = blockIdx.z;
  int tr = blockIdx.y * 128, tc = blockIdx.x * 128;
  int t = threadIdx.x;
  __shared__ __align__(16) unsigned short Ah[128*40], Al[128*40], Bh[128*40], Bl[128*40];
  f32x4 acc[4][4];
  #pragma unroll
  for (int i = 0; i < 4; ++i)
    #pragma unroll
    for (int j = 0; j < 4; ++j) acc[i][j] = (f32x4){0.f,0.f,0.f,0.f};
  int srow = t >> 1, skh = (t & 1) * 16;
  int l = t & 63, wv = t >> 6;
  int wr = (wv >> 1) * 64, wc = (wv & 1) * 64;
  int lr = l & 15, lg = l >> 4;
  for (int kk = 0; kk < 256; kk += 32){
    __syncthreads();
    split16(Wq + (size_t)(tr + srow)*256 + kk + skh, &Ah[srow*40 + skh], &Al[srow*40 + skh]);
    size_t gb = (size_t)b*65536 + (size_t)(tc + srow)*256 + kk + skh;
    *(us8*)&Bh[srow*40 + skh]     = *(const us8*)&Ghi[gb];
    *(us8*)&Bh[srow*40 + skh + 8] = *(const us8*)&Ghi[gb + 8];
    *(us8*)&Bl[srow*40 + skh]     = *(const us8*)&Glo[gb];
    *(us8*)&Bl[srow*40 + skh + 8] = *(const us8*)&Glo[gb + 8];
    __syncthreads();
    bf16x8 ah[4], alv[4], bh[4], blv[4];
    #pragma unroll
    for (int i = 0; i < 4; ++i){
      ah[i]  = ldbf8(&Ah[(wr + i*16 + lr)*40 + lg*8]);
      alv[i] = ldbf8(&Al[(wr + i*16 + lr)*40 + lg*8]);
      bh[i]  = ldbf8(&Bh[(wc + i*16 + lr)*40 + lg*8]);
      blv[i] = ldbf8(&Bl[(wc + i*16 + lr)*40 + lg*8]);
    }
    #pragma unroll
    for (int i = 0; i < 4; ++i)
      #pragma unroll
      for (int j = 0; j < 4; ++j){
        acc[i][j] = __builtin_amdgcn_mfma_f32_16x16x32_bf16(ah[i],  bh[j],  acc[i][j], 0,0,0);
        acc[i][j] = __builtin_amdgcn_mfma_f32_16x16x32_bf16(ah[i],  blv[j], acc[i][j], 0,0,0);
        acc[i][j] = __builtin_amdgcn_mfma_f32_16x16x32_bf16(alv[i], bh[j],  acc[i][j], 0,0,0);
      }
  }
  #pragma unroll
  for (int i = 0; i < 4; ++i)
    #pragma unroll
    for (int j = 0; j < 4; ++j)
      #pragma unroll
      for (int r = 0; r < 4; ++r){
        int row = tr + wr + i*16 + lg*4 + r;
        int col = tc + wc + j*16 + lr;
        size_t off = (size_t)b*65536 + (size_t)row*256 + col;
        float p = acc[i][j][r];
        unsigned short hp = f2bf(p);
        Phi[off] = hp;
        Plo[off] = f2bf(p - bf2f(hp));
      }
}

// ---------------- K4b: Ef_b = scale * P_b * Wk^T (split-bf16, 3-term) ----------
__global__ __launch_bounds__(256) void k_e(const unsigned short* __restrict__ Phi,
    const unsigned short* __restrict__ Plo, const float* __restrict__ Wk,
    float* __restrict__ Ef){
  int b = blockIdx.z;
  int tr = blockIdx.y * 128, tc = blockIdx.x * 128;
  int t = threadIdx.x;
  __shared__ __align__(16) unsigned short Ah[128*40], Al[128*40], Bh[128*40], Bl[128*40];
  f32x4 acc[4][4];
  #pragma unroll
  for (int i = 0; i < 4; ++i)
    #pragma unroll
    for (int j = 0; j < 4; ++j) acc[i][j] = (f32x4){0.f,0.f,0.f,0.f};
  int srow = t >> 1, skh = (t & 1) * 16;
  int l = t & 63, wv = t >> 6;
  int wr = (wv >> 1) * 64, wc = (wv & 1) * 64;
  int lr = l & 15, lg = l >> 4;
  for (int kk = 0; kk < 256; kk += 32){
    __syncthreads();
    size_t ga = (size_t)b*65536 + (size_t)(tr + srow)*256 + kk + skh;
    *(us8*)&Ah[srow*40 + skh]     = *(const us8*)&Phi[ga];
    *(us8*)&Ah[srow*40 + skh + 8] = *(const us8*)&Phi[ga + 8];
    *(us8*)&Al[srow*40 + skh]     = *(const us8*)&Plo[ga];
    *(us8*)&Al[srow*40 + skh + 8] = *(const us8*)&Plo[ga + 8];
    split16(Wk + (size_t)(tc + srow)*256 + kk + skh, &Bh[srow*40 + skh], &Bl[srow*40 + skh]);
    __syncthreads();
    bf16x8 ah[4], alv[4], bh[4], blv[4];
    #pragma unroll
    for (int i = 0; i < 4; ++i){
      ah[i]  = ldbf8(&Ah[(wr + i*16 + lr)*40 + lg*8]);
      alv[i] = ldbf8(&Al[(wr + i*16 + lr)*40 + lg*8]);
      bh[i]  = ldbf8(&Bh[(wc + i*16 + lr)*40 + lg*8]);
      blv[i] = ldbf8(&Bl[(wc + i*16 + lr)*40 + lg*8]);
    }
    #pragma unroll
    for (int i = 0; i < 4; ++i)
      #pragma unroll
      for (int j = 0; j < 4; ++j){
        acc[i][j] = __builtin_amdgcn_mfma_f32_16x16x32_bf16(ah[i],  bh[j],  acc[i][j], 0,0,0);
        acc[i][j] = __builtin_amdgcn_mfma_f32_16x16x32_bf16(ah[i],  blv[j], acc[i][j], 0,0,0);
        acc[i][j] = __builtin_amdgcn_mfma_f32_16x16x32_bf16(alv[i], bh[j],  acc[i][j], 0,0,0);
      }
  }
  #pragma unroll
  for (int i = 0; i < 4; ++i)
    #pragma unroll
    for (int j = 0; j < 4; ++j)
      #pragma unroll
      for (int r = 0; r < 4; ++r){
        int row = tr + wr + i*16 + lg*4 + r;
        int col = tc + wc + j*16 + lr;
        Ef[(size_t)b*65536 + (size_t)row*256 + col] = SCALE_E * acc[i][j][r];
      }
}

// ---------------- K4c: per-(b,h) softmax + M = gamma*attn@Wv + rowadd --------
__global__ __launch_bounds__(256) void k_soft(const float* __restrict__ Ef,
    const float* __restrict__ Wq, const float* __restrict__ bq,
    const float* __restrict__ Wk, const float* __restrict__ bk,
    const float* __restrict__ Wv, const float* __restrict__ bv,
    const float* __restrict__ gptr, const float* __restrict__ xsum,
    unsigned short* __restrict__ Mw, float* __restrict__ rowadd,
    float* __restrict__ attn_out){
  int blk = blockIdx.x, b = blk >> 3, h = blk & 7;
  int t = threadIdx.x;
  int i = t >> 3, j4 = (t & 7) * 4;
  __shared__ __align__(16) float Aw[32][40];
  __shared__ float qsv[32], ksv[32];
  // bias row sums (bq,bk are zero in this benchmark; kept for correctness)
  if (t < 64){
    int r = t & 31;
    const float* Wm = (t < 32) ? Wq : Wk;
    const float4* wr4 = (const float4*)(Wm + (size_t)(h*32 + r)*256);
    const float4* xs4 = (const float4*)(xsum + b*256);
    float s = 0.f;
    #pragma unroll
    for (int c4 = 0; c4 < 64; ++c4){
      float4 a = wr4[c4], xv = xs4[c4];
      s += a.x*xv.x + a.y*xv.y + a.z*xv.z + a.w*xv.w;
    }
    if (t < 32) qsv[r] = s; else ksv[r] = s;
  }
  __syncthreads();
  float4 e = *(const float4*)&Ef[(size_t)b*65536 + (size_t)(h*32 + i)*256 + h*32 + j4];
  float bqi = bq[h*32 + i];
  float qb  = qsv[i] + 4096.f * bqi;
  e.x += SCALE_E * (bqi*ksv[j4+0] + bk[h*32+j4+0]*qb);
  e.y += SCALE_E * (bqi*ksv[j4+1] + bk[h*32+j4+1]*qb);
  e.z += SCALE_E * (bqi*ksv[j4+2] + bk[h*32+j4+2]*qb);
  e.w += SCALE_E * (bqi*ksv[j4+3] + bk[h*32+j4+3]*qb);
  // row softmax across the 8 lanes holding this row
  float m = fmaxf(fmaxf(e.x, e.y), fmaxf(e.z, e.w));
  m = fmaxf(m, __shfl_xor(m, 1));
  m = fmaxf(m, __shfl_xor(m, 2));
  m = fmaxf(m, __shfl_xor(m, 4));
  float ex0 = expf(e.x - m), ex1 = expf(e.y - m), ex2 = expf(e.z - m), ex3 = expf(e.w - m);
  float s = ex0 + ex1 + ex2 + ex3;
  s += __shfl_xor(s, 1); s += __shfl_xor(s, 2); s += __shfl_xor(s, 4);
  float inv = 1.f / s;
  float4 a4 = { ex0*inv, ex1*inv, ex2*inv, ex3*inv };
  *(float4*)&attn_out[(((size_t)(b*8 + h))*32 + i)*32 + j4] = a4;
  *(float4*)&Aw[i][j4] = a4;
  __syncthreads();
  float gamma = gptr[0];
  float mr[32];
  #pragma unroll
  for (int r = 0; r < 32; ++r) mr[r] = 0.f;
  for (int j = 0; j < 32; ++j){
    float wvv = Wv[(size_t)(h*32 + j)*256 + t];
    #pragma unroll
    for (int r = 0; r < 32; ++r) mr[r] += Aw[r][j] * wvv;
  }
  unsigned short* Mrow = Mw + ((size_t)b*256 + h*32)*256 + t;
  #pragma unroll
  for (int r = 0; r < 32; ++r) Mrow[r*256] = f2bf(gamma * mr[r]);
  if (t < 32){
    float sr = 0.f;
    #pragma unroll
    for (int j = 0; j < 32; ++j) sr += Aw[t][j] * bv[h*32 + j];
    rowadd[b*256 + h*32 + t] = gamma * sr;
  }
}

// ---------------- K5/K6/K7: transposed-world GEMM, C^T = A(nxk) * B(256x256)^T --------
template<int MODE>
__global__ __launch_bounds__(256) void k_gemm(const unsigned short* __restrict__ Aall,
    const unsigned short* __restrict__ Bmat, const unsigned short* __restrict__ xthi,
    const float* __restrict__ rowadd, const float* __restrict__ bias,
    const float* __restrict__ betap, float* __restrict__ osc,
    unsigned short* __restrict__ outb){
  int b = blockIdx.z;
  int n0 = blockIdx.x * 128, o0 = blockIdx.y * 128;
  int t = threadIdx.x;
  __shared__ __align__(16) unsigned short Als[128*40], Bls[128*40];
  f32x4 acc[4][4];
  #pragma unroll
  for (int i = 0; i < 4; ++i)
    #pragma unroll
    for (int j = 0; j < 4; ++j) acc[i][j] = (f32x4){0.f,0.f,0.f,0.f};
  const unsigned short* A  = Aall + (size_t)b * 1048576;
  const unsigned short* Bp = (MODE == 0) ? (Bmat + (size_t)b * 65536) : Bmat;
  int srow = t >> 1, skh = (t & 1) * 16;
  int l = t & 63, wv = t >> 6;
  int wr = (wv >> 1) * 64, wc = (wv & 1) * 64;
  int lr = l & 15, lg = l >> 4;
  for (int kk = 0; kk < 256; kk += 32){
    __syncthreads();
    const unsigned short* ga = A  + (size_t)(n0 + srow)*256 + kk + skh;
    const unsigned short* gb = Bp + (size_t)(o0 + srow)*256 + kk + skh;
    *(us8*)&Als[srow*40 + skh]     = *(const us8*)ga;
    *(us8*)&Als[srow*40 + skh + 8] = *(const us8*)(ga + 8);
    *(us8*)&Bls[srow*40 + skh]     = *(const us8*)gb;
    *(us8*)&Bls[srow*40 + skh + 8] = *(const us8*)(gb + 8);
    __syncthreads();
    bf16x8 af[4], bfv[4];
    #pragma unroll
    for (int i = 0; i < 4; ++i) af[i]  = ldbf8(&Als[(wr + i*16 + lr)*40 + lg*8]);
    #pragma unroll
    for (int j = 0; j < 4; ++j) bfv[j] = ldbf8(&Bls[(wc + j*16 + lr)*40 + lg*8]);
    #pragma unroll
    for (int i = 0; i < 4; ++i)
      #pragma unroll
      for (int j = 0; j < 4; ++j)
        acc[i][j] = __builtin_amdgcn_mfma_f32_16x16x32_bf16(af[i], bfv[j], acc[i][j], 0,0,0);
  }
  float beta = (MODE == 2) ? betap[0] : 0.f;
  #pragma unroll
  for (int j = 0; j < 4; ++j){
    int oc = o0 + wc + j*16 + lr;
    float bvl = (MODE == 0) ? rowadd[b*256 + oc] : bias[oc];
    #pragma unroll
    for (int i = 0; i < 4; ++i){
      #pragma unroll
      for (int r = 0; r < 4; ++r){
        int n = n0 + wr + i*16 + lg*4 + r;
        size_t off = ((size_t)b*4096 + n)*256 + oc;
        float v = acc[i][j][r];
        if (MODE == 0){
          v += bf2f(xthi[off]) + bvl;
          osc[off] = v;
          outb[off] = f2bf(v);
        } else if (MODE == 1){
          v += bvl;
          v = (v > 0.f) ? v : 0.1f * v;
          outb[off] = f2bf(v);
        } else {
          v = osc[off] + beta * (v + bvl);
          outb[off] = f2bf(v);
        }
      }
    }
  }
}

// ---------------- K8: final^T [n][c] bf16 -> out [c][n] f32 ----------------
__global__ __launch_bounds__(256) void k_tpose(const unsigned short* __restrict__ fin,
                                               float* __restrict__ out){
  int b = blockIdx.z, c0 = blockIdx.y*64, n0 = blockIdx.x*64;
  int t = threadIdx.x, tn = t & 15, tc = t >> 4;
  __shared__ __align__(16) unsigned short ts[64][68];
  #pragma unroll
  for (int rr = 0; rr < 4; ++rr){
    int nl = rr*16 + tc;
    us4 v = *(const us4*)&fin[((size_t)(b*4096 + n0 + nl))*256 + c0 + tn*4];
    *(us4*)&ts[nl][tn*4] = v;
  }
  __syncthreads();
  #pragma unroll
  for (int rr = 0; rr < 4; ++rr){
    int cl = rr*16 + tc;
    int nl4 = tn*4;
    float4 v = { bf2f(ts[nl4+0][cl]), bf2f(ts[nl4+1][cl]),
                 bf2f(ts[nl4+2][cl]), bf2f(ts[nl4+3][cl]) };
    *(float4*)&out[((size_t)(b*256 + c0 + cl))*4096 + n0 + nl4] = v;
  }
}

// ---------------- launch ----------------
extern "C" void kernel_launch(void* const* d_in, const int* in_sizes, int n_in,
                              void* d_out, int out_size, void* d_ws, size_t ws_size,
                              hipStream_t stream){
  const float* x    = (const float*)d_in[0];
  const float* Wq   = (const float*)d_in[1];
  const float* bq   = (const float*)d_in[2];
  const float* Wk   = (const float*)d_in[3];
  const float* bk   = (const float*)d_in[4];
  const float* Wv   = (const float*)d_in[5];
  const float* bv   = (const float*)d_in[6];
  const float* gamma= (const float*)d_in[7];
  const float* beta = (const float*)d_in[8];
  const float* W1   = (const float*)d_in[9];
  const float* b1   = (const float*)d_in[10];
  const float* u1   = (const float*)d_in[11];
  const float* W2   = (const float*)d_in[12];
  const float* b2   = (const float*)d_in[13];
  const float* u2   = (const float*)d_in[14];

  char* ws = (char*)d_ws;
  unsigned short* xhi   = (unsigned short*)(ws + OFF_XHI);
  unsigned short* xlo   = (unsigned short*)(ws + OFF_XLO);
  unsigned short* xthi  = (unsigned short*)(ws + OFF_XTHI);
  float*          Gp    = (float*)(ws + OFF_GPART);
  float*          G0    = (float*)(ws + OFF_G);
  unsigned short* Mw    = (unsigned short*)(ws + OFF_M);
  unsigned short* W1s   = (unsigned short*)(ws + OFF_W1S);
  unsigned short* W2s   = (unsigned short*)(ws + OFF_W2S);
  float*          sig   = (float*)(ws + OFF_SIG);
  float*          xsum  = (float*)(ws + OFF_XSUM);
  float*          rowadd= (float*)(ws + OFF_ROWADD);
  // aliases (lifetimes disjoint):
  unsigned short* Ghi   = (unsigned short*)(ws + OFF_XLO);            // after k_gram
  unsigned short* Glo   = (unsigned short*)(ws + OFF_XLO + 2097152);
  unsigned short* Phi   = (unsigned short*)(ws + OFF_GPART);          // after k_gred
  unsigned short* Plo   = (unsigned short*)(ws + OFF_GPART + 2097152);
  float*          Ef    = (float*)(ws + OFF_GPART + 4194304);
  unsigned short* othi  = xlo;    // O^T bf16, written K5 (after Ghi/Glo consumed)
  unsigned short* y1t   = xhi;    // y1^T bf16, written K6
  unsigned short* finT  = xthi;   // final^T bf16, written K7

  float* outF  = (float*)d_out;
  float* attnO = outF + 16777216;   // second output (attn)
  float* osc   = outF;              // O^T f32 scratch inside d_out[0:16M)

  k_zero<<<dim3(16), dim3(256), 0, stream>>>(xsum);
  k_sigma<<<dim3(2), dim3(256), 0, stream>>>(W1, u1, W2, u2, sig);
  k_wconv<<<dim3(128), dim3(256), 0, stream>>>(W1, W2, sig, W1s, W2s);
  k_convert<<<dim3(64,4,16), dim3(256), 0, stream>>>(x, xhi, xlo, xthi, xsum);
  k_gram<<<dim3(4,4,16), dim3(256), 0, stream>>>(xhi, xlo, G0, Gp);
  k_gred<<<dim3(1024), dim3(256), 0, stream>>>(G0, Gp, Ghi, Glo);
  k_qg<<<dim3(2,2,16), dim3(256), 0, stream>>>(Wq, Ghi, Glo, Phi, Plo);
  k_e<<<dim3(2,2,16), dim3(256), 0, stream>>>(Phi, Plo, Wk, Ef);
  k_soft<<<dim3(128), dim3(256), 0, stream>>>(Ef, Wq, bq, Wk, bk, Wv, bv,
                                              gamma, xsum, Mw, rowadd, attnO);
  k_gemm<0><<<dim3(32,2,16), dim3(256), 0, stream>>>(xthi, Mw, xthi, rowadd, b1, beta, osc, othi);
  k_gemm<1><<<dim3(32,2,16), dim3(256), 0, stream>>>(othi, W1s, xthi, rowadd, b1, beta, osc, y1t);
  k_gemm<2><<<dim3(32,2,16), dim3(256), 0, stream>>>(y1t, W2s, xthi, rowadd, b2, beta, osc, finT);
  k_tpose<<<dim3(64,4,16), dim3(256), 0, stream>>>(finT, outF);
}

// Round 4
// 371.821 us; speedup vs baseline: 1.2005x; 1.1418x over previous
//
#include <hip/hip_runtime.h>
#include <hip/hip_bf16.h>
#include <cstdint>
#include <cstddef>

// ---------------- types / helpers ----------------
typedef __attribute__((ext_vector_type(8))) __bf16 bf16x8;
typedef __attribute__((ext_vector_type(4))) float f32x4;
typedef __attribute__((ext_vector_type(8))) unsigned short us8;
typedef __attribute__((ext_vector_type(4))) unsigned short us4;

__device__ __forceinline__ unsigned short f2bf(float f){
  unsigned int u = __float_as_uint(f);
  u += 0x7fffu + ((u >> 16) & 1u);      // RNE
  return (unsigned short)(u >> 16);
}
__device__ __forceinline__ float bf2f(unsigned short h){
  return __uint_as_float(((unsigned int)h) << 16);
}
__device__ __forceinline__ bf16x8 ldbf8(const unsigned short* p){
  return __builtin_bit_cast(bf16x8, *(const us8*)p);
}
// split 16 consecutive f32 into bf16 hi/lo halves (for LDS staging)
__device__ __forceinline__ void split16(const float* __restrict__ g,
                                        unsigned short* __restrict__ hs,
                                        unsigned short* __restrict__ ls){
  #pragma unroll
  for (int q = 0; q < 4; ++q){
    float4 v = *(const float4*)(g + q*4);
    unsigned short h0=f2bf(v.x), h1=f2bf(v.y), h2=f2bf(v.z), h3=f2bf(v.w);
    us4 hv = {h0,h1,h2,h3};
    us4 lv = { f2bf(v.x - bf2f(h0)), f2bf(v.y - bf2f(h1)),
               f2bf(v.z - bf2f(h2)), f2bf(v.w - bf2f(h3)) };
    *(us4*)(hs + q*4) = hv;
    *(us4*)(ls + q*4) = lv;
  }
}

#define SCALE_E 0.35355339059327373f   // HEADS^-0.5

// ---------------- workspace layout (bytes) ----------------
static const size_t OFF_XHI    = 0;               // u16 [16][256][4096]  (later: y1t)
static const size_t OFF_XLO    = 33554432;        // u16 [16][256][4096]  (later: Ghi/Glo, then othi)
static const size_t OFF_XTHI   = 67108864;        // u16 [16][4096][256]  (later: finalT)
static const size_t OFF_GPART  = 100663296;       // f32 [3][16][256][256] (later: Phi/Plo/Ef)
static const size_t OFF_G      = 113246208;       // f32 [16][256][256]  (gram partial 0)
static const size_t OFF_M      = 117440512;       // u16 [16][256][256]
static const size_t OFF_W1S    = 119537664;       // u16 [256][256]
static const size_t OFF_W2S    = 119668736;       // u16 [256][256]
static const size_t OFF_SIG    = 119799808;       // f32 [4]
static const size_t OFF_XSUM   = 119799824;       // f32 [16][256]
static const size_t OFF_ROWADD = 119816208;       // f32 [16][256]

// ---------------- K0: zero xsum ----------------
__global__ void k_zero(float* __restrict__ xsum){
  xsum[blockIdx.x * 256 + threadIdx.x] = 0.f;
}

// ---------------- K1: spectral-norm sigmas (2 blocks) ----------------
__global__ void k_sigma(const float* __restrict__ W1, const float* __restrict__ u1,
                        const float* __restrict__ W2, const float* __restrict__ u2,
                        float* __restrict__ sig){
  const float* W = blockIdx.x ? W2 : W1;
  const float* u = blockIdx.x ? u2 : u1;
  int t = threadIdx.x;
  __shared__ __align__(16) float red[256];
  __shared__ __align__(16) float vls[256];
  __shared__ __align__(16) float uls[256];
  uls[t] = u[t];
  __syncthreads();
  float t1 = 0.f;
  for (int o = 0; o < 256; ++o) t1 += W[o*256 + t] * uls[o];
  red[t] = t1 * t1;
  __syncthreads();
  for (int s = 128; s > 0; s >>= 1){ if (t < s) red[t] += red[t+s]; __syncthreads(); }
  float nrm = sqrtf(red[0]);
  vls[t] = t1 / (nrm + 1e-12f);
  __syncthreads();
  float w = 0.f;
  const float4* wr4 = (const float4*)(W + t*256);
  for (int c4 = 0; c4 < 64; ++c4){
    float4 a = wr4[c4];
    float4 v = *(const float4*)&vls[c4*4];
    w += a.x*v.x + a.y*v.y + a.z*v.z + a.w*v.w;
  }
  __syncthreads();
  red[t] = w * w;
  __syncthreads();
  for (int s = 128; s > 0; s >>= 1){ if (t < s) red[t] += red[t+s]; __syncthreads(); }
  if (t == 0){
    float s2 = red[0];
    float sn = sqrtf(s2);
    sig[blockIdx.x] = s2 / (sn + 1e-12f);
  }
}

// ---------------- K1b: W1/sigma1, W2/sigma2 -> bf16 ----------------
__global__ void k_wconv(const float* __restrict__ W1, const float* __restrict__ W2,
                        const float* __restrict__ sig,
                        unsigned short* __restrict__ W1s, unsigned short* __restrict__ W2s){
  int sel = blockIdx.x >> 6;
  const float* W = sel ? W2 : W1;
  unsigned short* o = sel ? W2s : W1s;
  float inv = 1.0f / sig[sel];
  int base = (blockIdx.x & 63) * 1024 + threadIdx.x * 4;
  float4 v = *(const float4*)&W[base];
  us4 r = { f2bf(v.x*inv), f2bf(v.y*inv), f2bf(v.z*inv), f2bf(v.w*inv) };
  *(us4*)&o[base] = r;
}

// ---------------- K2: x -> xhi/xlo ([c][n]) + xthi ([n][c]) + row sums ----------------
__global__ __launch_bounds__(256) void k_convert(const float* __restrict__ x,
    unsigned short* __restrict__ xhi, unsigned short* __restrict__ xlo,
    unsigned short* __restrict__ xthi, float* __restrict__ xsum){
  int b = blockIdx.z, c0 = blockIdx.y*64, n0 = blockIdx.x*64;
  int t = threadIdx.x, tn = t & 15, tc = t >> 4;
  __shared__ __align__(16) unsigned short hs[64][68];
  __shared__ __align__(16) float ps[64][17];
  #pragma unroll
  for (int rr = 0; rr < 4; ++rr){
    int cl = rr*16 + tc;
    size_t gro = ((size_t)(b*256 + c0 + cl))*4096 + n0 + tn*4;
    float4 v = *(const float4*)&x[gro];
    unsigned short h0=f2bf(v.x), h1=f2bf(v.y), h2=f2bf(v.z), h3=f2bf(v.w);
    us4 hv = {h0,h1,h2,h3};
    us4 lv = { f2bf(v.x - bf2f(h0)), f2bf(v.y - bf2f(h1)),
               f2bf(v.z - bf2f(h2)), f2bf(v.w - bf2f(h3)) };
    *(us4*)&xhi[gro] = hv;
    *(us4*)&xlo[gro] = lv;
    *(us4*)&hs[cl][tn*4] = hv;
    ps[cl][tn] = v.x + v.y + v.z + v.w;
  }
  __syncthreads();
  #pragma unroll
  for (int rr = 0; rr < 4; ++rr){
    int nl = rr*16 + tc;
    int cl4 = tn*4;
    us4 w = { hs[cl4+0][nl], hs[cl4+1][nl], hs[cl4+2][nl], hs[cl4+3][nl] };
    *(us4*)&xthi[((size_t)(b*4096 + n0 + nl))*256 + c0 + cl4] = w;
  }
  if (t < 64){
    float s = 0.f;
    #pragma unroll
    for (int k = 0; k < 16; ++k) s += ps[t][k];
    atomicAdd(&xsum[b*256 + c0 + t], s);
  }
}

// ---------------- K3: Gram G_b = X X^T in split-bf16 MFMA (reg-prefetch dbuf) ------
__global__ __launch_bounds__(256) void k_gram(const unsigned short* __restrict__ xhi,
    const unsigned short* __restrict__ xlo, float* __restrict__ G, float* __restrict__ Gp){
  int b = blockIdx.z;
  int tr = (blockIdx.y >> 1) * 128, tc = (blockIdx.y & 1) * 128;
  int kc = blockIdx.x * 1024;
  int t = threadIdx.x;
  __shared__ __align__(16) unsigned short Ah[2][128*40], Al[2][128*40],
                                          Bh[2][128*40], Bl[2][128*40];
  f32x4 acc[4][4];
  #pragma unroll
  for (int i = 0; i < 4; ++i)
    #pragma unroll
    for (int j = 0; j < 4; ++j) acc[i][j] = (f32x4){0.f,0.f,0.f,0.f};
  int srow = t >> 1, skh = (t & 1) * 16;
  int l = t & 63, wv = t >> 6;
  int wr = (wv >> 1) * 64, wc = (wv & 1) * 64;
  int lr = l & 15, lg = l >> 4;
  size_t bb = (size_t)b * 256 * 4096;
  const unsigned short* gah = xhi + bb + (size_t)(tr + srow)*4096 + kc + skh;
  const unsigned short* gal = xlo + bb + (size_t)(tr + srow)*4096 + kc + skh;
  const unsigned short* gbh = xhi + bb + (size_t)(tc + srow)*4096 + kc + skh;
  const unsigned short* gbl = xlo + bb + (size_t)(tc + srow)*4096 + kc + skh;
  us8 rah0 = *(const us8*)gah, rah1 = *(const us8*)(gah + 8);
  us8 ral0 = *(const us8*)gal, ral1 = *(const us8*)(gal + 8);
  us8 rbh0 = *(const us8*)gbh, rbh1 = *(const us8*)(gbh + 8);
  us8 rbl0 = *(const us8*)gbl, rbl1 = *(const us8*)(gbl + 8);
  int cur = 0;
  for (int ki = 0; ki < 32; ++ki){
    *(us8*)&Ah[cur][srow*40 + skh]     = rah0;
    *(us8*)&Ah[cur][srow*40 + skh + 8] = rah1;
    *(us8*)&Al[cur][srow*40 + skh]     = ral0;
    *(us8*)&Al[cur][srow*40 + skh + 8] = ral1;
    *(us8*)&Bh[cur][srow*40 + skh]     = rbh0;
    *(us8*)&Bh[cur][srow*40 + skh + 8] = rbh1;
    *(us8*)&Bl[cur][srow*40 + skh]     = rbl0;
    *(us8*)&Bl[cur][srow*40 + skh + 8] = rbl1;
    if (ki < 31){
      int ko = (ki + 1) * 32;
      rah0 = *(const us8*)(gah + ko); rah1 = *(const us8*)(gah + ko + 8);
      ral0 = *(const us8*)(gal + ko); ral1 = *(const us8*)(gal + ko + 8);
      rbh0 = *(const us8*)(gbh + ko); rbh1 = *(const us8*)(gbh + ko + 8);
      rbl0 = *(const us8*)(gbl + ko); rbl1 = *(const us8*)(gbl + ko + 8);
    }
    __syncthreads();
    bf16x8 ah[4], alv[4], bh[4], blv[4];
    #pragma unroll
    for (int i = 0; i < 4; ++i){
      ah[i]  = ldbf8(&Ah[cur][(wr + i*16 + lr)*40 + lg*8]);
      alv[i] = ldbf8(&Al[cur][(wr + i*16 + lr)*40 + lg*8]);
      bh[i]  = ldbf8(&Bh[cur][(wc + i*16 + lr)*40 + lg*8]);
      blv[i] = ldbf8(&Bl[cur][(wc + i*16 + lr)*40 + lg*8]);
    }
    #pragma unroll
    for (int i = 0; i < 4; ++i)
      #pragma unroll
      for (int j = 0; j < 4; ++j){
        acc[i][j] = __builtin_amdgcn_mfma_f32_16x16x32_bf16(ah[i],  bh[j],  acc[i][j], 0,0,0);
        acc[i][j] = __builtin_amdgcn_mfma_f32_16x16x32_bf16(ah[i],  blv[j], acc[i][j], 0,0,0);
        acc[i][j] = __builtin_amdgcn_mfma_f32_16x16x32_bf16(alv[i], bh[j],  acc[i][j], 0,0,0);
      }
    cur ^= 1;
  }
  float* dst = (blockIdx.x == 0) ? (G + (size_t)b*65536)
                                 : (Gp + ((size_t)(blockIdx.x - 1)*16 + b)*65536);
  #pragma unroll
  for (int i = 0; i < 4; ++i)
    #pragma unroll
    for (int j = 0; j < 4; ++j)
      #pragma unroll
      for (int r = 0; r < 4; ++r){
        int row = tr + wr + i*16 + lg*4 + r;
        int col = tc + wc + j*16 + lr;
        dst[row*256 + col] = acc[i][j][r];
      }
}

// ---------------- K3b: G = sum of 4 partials -> bf16 hi/lo ----------------
__global__ void k_gred(const float* __restrict__ G0, const float* __restrict__ Gp,
                       unsigned short* __restrict__ Ghi, unsigned short* __restrict__ Glo){
  size_t idx = ((size_t)blockIdx.x * 256 + threadIdx.x) * 4;
  float4 g  = *(const float4*)&G0[idx];
  float4 p0 = *(const float4*)&Gp[idx];
  float4 p1 = *(const float4*)&Gp[idx + 1048576];
  float4 p2 = *(const float4*)&Gp[idx + 2097152];
  float s0 = g.x + p0.x + p1.x + p2.x;
  float s1 = g.y + p0.y + p1.y + p2.y;
  float s2 = g.z + p0.z + p1.z + p2.z;
  float s3 = g.w + p0.w + p1.w + p2.w;
  unsigned short h0=f2bf(s0), h1=f2bf(s1), h2=f2bf(s2), h3=f2bf(s3);
  us4 hv = {h0,h1,h2,h3};
  us4 lv = { f2bf(s0 - bf2f(h0)), f2bf(s1 - bf2f(h1)),
             f2bf(s2 - bf2f(h2)), f2bf(s3 - bf2f(h3)) };
  *(us4*)&Ghi[idx] = hv;
  *(us4*)&Glo[idx] = lv;
}

// ---------------- K4a: P_b = Wq * G_b (split-bf16, 3-term), out hi/lo bf16 --------
__global__ __launch_bounds__(256) void k_qg(const float* __restrict__ Wq,
    const unsigned short* __restrict__ Ghi, const unsigned short* __restrict__ Glo,
    unsigned short* __restrict__ Phi, unsigned short* __restrict__ Plo){
  int b = blockIdx.z;
  int tr = blockIdx.y * 128, tc = blockIdx.x * 128;
  int t = threadIdx.x;
  __shared__ __align__(16) unsigned short Ah[128*40], Al[128*40], Bh[128*40], Bl[128*40];
  f32x4 acc[4][4];
  #pragma unroll
  for (int i = 0; i < 4; ++i)
    #pragma unroll
    for (int j = 0; j < 4; ++j) acc[i][j] = (f32x4){0.f,0.f,0.f,0.f};
  int srow = t >> 1, skh = (t & 1) * 16;
  int l = t & 63, wv = t >> 6;
  int wr = (wv >> 1) * 64, wc = (wv & 1) * 64;
  int lr = l & 15, lg = l >> 4;
  for (int kk = 0; kk < 256; kk += 32){
    __syncthreads();
    split16(Wq + (size_t)(tr + srow)*256 + kk + skh, &Ah[srow*40 + skh], &Al[srow*40 + skh]);
    size_t gb = (size_t)b*65536 + (size_t)(tc + srow)*256 + kk + skh;
    *(us8*)&Bh[srow*40 + skh]     = *(const us8*)&Ghi[gb];
    *(us8*)&Bh[srow*40 + skh + 8] = *(const us8*)&Ghi[gb + 8];
    *(us8*)&Bl[srow*40 + skh]     = *(const us8*)&Glo[gb];
    *(us8*)&Bl[srow*40 + skh + 8] = *(const us8*)&Glo[gb + 8];
    __syncthreads();
    bf16x8 ah[4], alv[4], bh[4], blv[4];
    #pragma unroll
    for (int i = 0; i < 4; ++i){
      ah[i]  = ldbf8(&Ah[(wr + i*16 + lr)*40 + lg*8]);
      alv[i] = ldbf8(&Al[(wr + i*16 + lr)*40 + lg*8]);
      bh[i]  = ldbf8(&Bh[(wc + i*16 + lr)*40 + lg*8]);
      blv[i] = ldbf8(&Bl[(wc + i*16 + lr)*40 + lg*8]);
    }
    #pragma unroll
    for (int i = 0; i < 4; ++i)
      #pragma unroll
      for (int j = 0; j < 4; ++j){
        acc[i][j] = __builtin_amdgcn_mfma_f32_16x16x32_bf16(ah[i],  bh[j],  acc[i][j], 0,0,0);
        acc[i][j] = __builtin_amdgcn_mfma_f32_16x16x32_bf16(ah[i],  blv[j], acc[i][j], 0,0,0);
        acc[i][j] = __builtin_amdgcn_mfma_f32_16x16x32_bf16(alv[i], bh[j],  acc[i][j], 0,0,0);
      }
  }
  #pragma unroll
  for (int i = 0; i < 4; ++i)
    #pragma unroll
    for (int j = 0; j < 4; ++j)
      #pragma unroll
      for (int r = 0; r < 4; ++r){
        int row = tr + wr + i*16 + lg*4 + r;
        int col = tc + wc + j*16 + lr;
        size_t off = (size_t)b*65536 + (size_t)row*256 + col;
        float p = acc[i][j][r];
        unsigned short hp = f2bf(p);
        Phi[off] = hp;
        Plo[off] = f2bf(p - bf2f(hp));
      }
}

// ---------------- K4b: Ef_b = scale * P_b * Wk^T (split-bf16, 3-term) ----------
__global__ __launch_bounds__(256) void k_e(const unsigned short* __restrict__ Phi,
    const unsigned short* __restrict__ Plo, const float* __restrict__ Wk,
    float* __restrict__ Ef){
  int b = blockIdx.z;
  int tr = blockIdx.y * 128, tc = blockIdx.x * 128;
  int t = threadIdx.x;
  __shared__ __align__(16) unsigned short Ah[128*40], Al[128*40], Bh[128*40], Bl[128*40];
  f32x4 acc[4][4];
  #pragma unroll
  for (int i = 0; i < 4; ++i)
    #pragma unroll
    for (int j = 0; j < 4; ++j) acc[i][j] = (f32x4){0.f,0.f,0.f,0.f};
  int srow = t >> 1, skh = (t & 1) * 16;
  int l = t & 63, wv = t >> 6;
  int wr = (wv >> 1) * 64, wc = (wv & 1) * 64;
  int lr = l & 15, lg = l >> 4;
  for (int kk = 0; kk < 256; kk += 32){
    __syncthreads();
    size_t ga = (size_t)b*65536 + (size_t)(tr + srow)*256 + kk + skh;
    *(us8*)&Ah[srow*40 + skh]     = *(const us8*)&Phi[ga];
    *(us8*)&Ah[srow*40 + skh + 8] = *(const us8*)&Phi[ga + 8];
    *(us8*)&Al[srow*40 + skh]     = *(const us8*)&Plo[ga];
    *(us8*)&Al[srow*40 + skh + 8] = *(const us8*)&Plo[ga + 8];
    split16(Wk + (size_t)(tc + srow)*256 + kk + skh, &Bh[srow*40 + skh], &Bl[srow*40 + skh]);
    __syncthreads();
    bf16x8 ah[4], alv[4], bh[4], blv[4];
    #pragma unroll
    for (int i = 0; i < 4; ++i){
      ah[i]  = ldbf8(&Ah[(wr + i*16 + lr)*40 + lg*8]);
      alv[i] = ldbf8(&Al[(wr + i*16 + lr)*40 + lg*8]);
      bh[i]  = ldbf8(&Bh[(wc + i*16 + lr)*40 + lg*8]);
      blv[i] = ldbf8(&Bl[(wc + i*16 + lr)*40 + lg*8]);
    }
    #pragma unroll
    for (int i = 0; i < 4; ++i)
      #pragma unroll
      for (int j = 0; j < 4; ++j){
        acc[i][j] = __builtin_amdgcn_mfma_f32_16x16x32_bf16(ah[i],  bh[j],  acc[i][j], 0,0,0);
        acc[i][j] = __builtin_amdgcn_mfma_f32_16x16x32_bf16(ah[i],  blv[j], acc[i][j], 0,0,0);
        acc[i][j] = __builtin_amdgcn_mfma_f32_16x16x32_bf16(alv[i], bh[j],  acc[i][j], 0,0,0);
      }
  }
  #pragma unroll
  for (int i = 0; i < 4; ++i)
    #pragma unroll
    for (int j = 0; j < 4; ++j)
      #pragma unroll
      for (int r = 0; r < 4; ++r){
        int row = tr + wr + i*16 + lg*4 + r;
        int col = tc + wc + j*16 + lr;
        Ef[(size_t)b*65536 + (size_t)row*256 + col] = SCALE_E * acc[i][j][r];
      }
}

// ---------------- K4c: per-(b,h) softmax + M = gamma*attn@Wv + I + rowadd --------
__global__ __launch_bounds__(256) void k_soft(const float* __restrict__ Ef,
    const float* __restrict__ Wq, const float* __restrict__ bq,
    const float* __restrict__ Wk, const float* __restrict__ bk,
    const float* __restrict__ Wv, const float* __restrict__ bv,
    const float* __restrict__ gptr, const float* __restrict__ xsum,
    unsigned short* __restrict__ Mw, float* __restrict__ rowadd,
    float* __restrict__ attn_out){
  int blk = blockIdx.x, b = blk >> 3, h = blk & 7;
  int t = threadIdx.x;
  int i = t >> 3, j4 = (t & 7) * 4;
  __shared__ __align__(16) float Aw[32][40];
  __shared__ float qsv[32], ksv[32];
  if (t < 64){
    int r = t & 31;
    const float* Wm = (t < 32) ? Wq : Wk;
    const float4* wr4 = (const float4*)(Wm + (size_t)(h*32 + r)*256);
    const float4* xs4 = (const float4*)(xsum + b*256);
    float s = 0.f;
    #pragma unroll
    for (int c4 = 0; c4 < 64; ++c4){
      float4 a = wr4[c4], xv = xs4[c4];
      s += a.x*xv.x + a.y*xv.y + a.z*xv.z + a.w*xv.w;
    }
    if (t < 32) qsv[r] = s; else ksv[r] = s;
  }
  __syncthreads();
  float4 e = *(const float4*)&Ef[(size_t)b*65536 + (size_t)(h*32 + i)*256 + h*32 + j4];
  float bqi = bq[h*32 + i];
  float qb  = qsv[i] + 4096.f * bqi;
  e.x += SCALE_E * (bqi*ksv[j4+0] + bk[h*32+j4+0]*qb);
  e.y += SCALE_E * (bqi*ksv[j4+1] + bk[h*32+j4+1]*qb);
  e.z += SCALE_E * (bqi*ksv[j4+2] + bk[h*32+j4+2]*qb);
  e.w += SCALE_E * (bqi*ksv[j4+3] + bk[h*32+j4+3]*qb);
  float m = fmaxf(fmaxf(e.x, e.y), fmaxf(e.z, e.w));
  m = fmaxf(m, __shfl_xor(m, 1));
  m = fmaxf(m, __shfl_xor(m, 2));
  m = fmaxf(m, __shfl_xor(m, 4));
  float ex0 = expf(e.x - m), ex1 = expf(e.y - m), ex2 = expf(e.z - m), ex3 = expf(e.w - m);
  float s = ex0 + ex1 + ex2 + ex3;
  s += __shfl_xor(s, 1); s += __shfl_xor(s, 2); s += __shfl_xor(s, 4);
  float inv = 1.f / s;
  float4 a4 = { ex0*inv, ex1*inv, ex2*inv, ex3*inv };
  *(float4*)&attn_out[(((size_t)(b*8 + h))*32 + i)*32 + j4] = a4;
  *(float4*)&Aw[i][j4] = a4;
  __syncthreads();
  float gamma = gptr[0];
  float mr[32];
  #pragma unroll
  for (int r = 0; r < 32; ++r) mr[r] = 0.f;
  for (int j = 0; j < 32; ++j){
    float wvv = Wv[(size_t)(h*32 + j)*256 + t];
    #pragma unroll
    for (int r = 0; r < 32; ++r) mr[r] += Aw[r][j] * wvv;
  }
  unsigned short* Mrow = Mw + ((size_t)b*256 + h*32)*256 + t;
  #pragma unroll
  for (int r = 0; r < 32; ++r){
    float diag = (h*32 + r == t) ? 1.f : 0.f;   // fold +X residual: M2 = gamma*attn@Wv + I
    Mrow[r*256] = f2bf(gamma * mr[r] + diag);
  }
  if (t < 32){
    float sr = 0.f;
    #pragma unroll
    for (int j = 0; j < 32; ++j) sr += Aw[t][j] * bv[h*32 + j];
    rowadd[b*256 + h*32 + t] = gamma * sr;
  }
}

// ---------------- K5/K6/K7: transposed-world GEMM with reg-prefetch dbuf ----------
// C^T = A(4096x256) * B(256x256)^T per batch
// MODE 0: O^T = X^T (M+I)^T + rowadd           -> othi (bf16)
// MODE 1: y1^T = lrelu(O^T W1s^T + b1)         -> y1t  (bf16)
// MODE 2: final^T = O^T + beta*(y1^T W2s^T+b2) -> finT (bf16)
template<int MODE>
__global__ __launch_bounds__(256) void k_gemm(const unsigned short* __restrict__ Aall,
    const unsigned short* __restrict__ Bmat, const unsigned short* __restrict__ oth,
    const float* __restrict__ rowadd, const float* __restrict__ bias,
    const float* __restrict__ betap,
    unsigned short* __restrict__ outb){
  int b = blockIdx.z;
  int n0 = blockIdx.x * 128, o0 = blockIdx.y * 128;
  int t = threadIdx.x;
  __shared__ __align__(16) unsigned short Als[2][128*40], Bls[2][128*40];
  f32x4 acc[4][4];
  #pragma unroll
  for (int i = 0; i < 4; ++i)
    #pragma unroll
    for (int j = 0; j < 4; ++j) acc[i][j] = (f32x4){0.f,0.f,0.f,0.f};
  const unsigned short* A  = Aall + (size_t)b * 1048576;
  const unsigned short* Bp = (MODE == 0) ? (Bmat + (size_t)b * 65536) : Bmat;
  int srow = t >> 1, skh = (t & 1) * 16;
  int l = t & 63, wv = t >> 6;
  int wr = (wv >> 1) * 64, wc = (wv & 1) * 64;
  int lr = l & 15, lg = l >> 4;
  const unsigned short* ga = A  + (size_t)(n0 + srow)*256 + skh;
  const unsigned short* gb = Bp + (size_t)(o0 + srow)*256 + skh;
  us8 ra0 = *(const us8*)ga, ra1 = *(const us8*)(ga + 8);
  us8 rb0 = *(const us8*)gb, rb1 = *(const us8*)(gb + 8);
  #pragma unroll
  for (int ki = 0; ki < 8; ++ki){
    int cur = ki & 1;
    *(us8*)&Als[cur][srow*40 + skh]     = ra0;
    *(us8*)&Als[cur][srow*40 + skh + 8] = ra1;
    *(us8*)&Bls[cur][srow*40 + skh]     = rb0;
    *(us8*)&Bls[cur][srow*40 + skh + 8] = rb1;
    if (ki < 7){
      int ko = (ki + 1) * 32;
      ra0 = *(const us8*)(ga + ko); ra1 = *(const us8*)(ga + ko + 8);
      rb0 = *(const us8*)(gb + ko); rb1 = *(const us8*)(gb + ko + 8);
    }
    __syncthreads();
    bf16x8 af[4], bfv[4];
    #pragma unroll
    for (int i = 0; i < 4; ++i) af[i]  = ldbf8(&Als[cur][(wr + i*16 + lr)*40 + lg*8]);
    #pragma unroll
    for (int j = 0; j < 4; ++j) bfv[j] = ldbf8(&Bls[cur][(wc + j*16 + lr)*40 + lg*8]);
    #pragma unroll
    for (int i = 0; i < 4; ++i)
      #pragma unroll
      for (int j = 0; j < 4; ++j)
        acc[i][j] = __builtin_amdgcn_mfma_f32_16x16x32_bf16(af[i], bfv[j], acc[i][j], 0,0,0);
  }
  float beta = (MODE == 2) ? betap[0] : 0.f;
  #pragma unroll
  for (int j = 0; j < 4; ++j){
    int oc = o0 + wc + j*16 + lr;
    float bvl = (MODE == 0) ? rowadd[b*256 + oc] : bias[oc];
    #pragma unroll
    for (int i = 0; i < 4; ++i){
      #pragma unroll
      for (int r = 0; r < 4; ++r){
        int n = n0 + wr + i*16 + lg*4 + r;
        size_t off = ((size_t)b*4096 + n)*256 + oc;
        float v = acc[i][j][r];
        if (MODE == 0){
          v += bvl;
          outb[off] = f2bf(v);
        } else if (MODE == 1){
          v += bvl;
          v = (v > 0.f) ? v : 0.1f * v;
          outb[off] = f2bf(v);
        } else {
          v = bf2f(oth[off]) + beta * (v + bvl);
          outb[off] = f2bf(v);
        }
      }
    }
  }
}

// ---------------- K8: final^T [n][c] bf16 -> out [c][n] f32 ----------------
__global__ __launch_bounds__(256) void k_tpose(const unsigned short* __restrict__ fin,
                                               float* __restrict__ out){
  int b = blockIdx.z, c0 = blockIdx.y*64, n0 = blockIdx.x*64;
  int t = threadIdx.x, tn = t & 15, tc = t >> 4;
  __shared__ __align__(16) unsigned short ts[64][68];
  #pragma unroll
  for (int rr = 0; rr < 4; ++rr){
    int nl = rr*16 + tc;
    us4 v = *(const us4*)&fin[((size_t)(b*4096 + n0 + nl))*256 + c0 + tn*4];
    *(us4*)&ts[nl][tn*4] = v;
  }
  __syncthreads();
  #pragma unroll
  for (int rr = 0; rr < 4; ++rr){
    int cl = rr*16 + tc;
    int nl4 = tn*4;
    float4 v = { bf2f(ts[nl4+0][cl]), bf2f(ts[nl4+1][cl]),
                 bf2f(ts[nl4+2][cl]), bf2f(ts[nl4+3][cl]) };
    *(float4*)&out[((size_t)(b*256 + c0 + cl))*4096 + n0 + nl4] = v;
  }
}

// ---------------- launch ----------------
extern "C" void kernel_launch(void* const* d_in, const int* in_sizes, int n_in,
                              void* d_out, int out_size, void* d_ws, size_t ws_size,
                              hipStream_t stream){
  const float* x    = (const float*)d_in[0];
  const float* Wq   = (const float*)d_in[1];
  const float* bq   = (const float*)d_in[2];
  const float* Wk   = (const float*)d_in[3];
  const float* bk   = (const float*)d_in[4];
  const float* Wv   = (const float*)d_in[5];
  const float* bv   = (const float*)d_in[6];
  const float* gamma= (const float*)d_in[7];
  const float* beta = (const float*)d_in[8];
  const float* W1   = (const float*)d_in[9];
  const float* b1   = (const float*)d_in[10];
  const float* u1   = (const float*)d_in[11];
  const float* W2   = (const float*)d_in[12];
  const float* b2   = (const float*)d_in[13];
  const float* u2   = (const float*)d_in[14];

  char* ws = (char*)d_ws;
  unsigned short* xhi   = (unsigned short*)(ws + OFF_XHI);
  unsigned short* xlo   = (unsigned short*)(ws + OFF_XLO);
  unsigned short* xthi  = (unsigned short*)(ws + OFF_XTHI);
  float*          Gp    = (float*)(ws + OFF_GPART);
  float*          G0    = (float*)(ws + OFF_G);
  unsigned short* Mw    = (unsigned short*)(ws + OFF_M);
  unsigned short* W1s   = (unsigned short*)(ws + OFF_W1S);
  unsigned short* W2s   = (unsigned short*)(ws + OFF_W2S);
  float*          sig   = (float*)(ws + OFF_SIG);
  float*          xsum  = (float*)(ws + OFF_XSUM);
  float*          rowadd= (float*)(ws + OFF_ROWADD);
  // aliases (lifetimes disjoint):
  unsigned short* Ghi   = (unsigned short*)(ws + OFF_XLO);            // after k_gram
  unsigned short* Glo   = (unsigned short*)(ws + OFF_XLO + 2097152);
  unsigned short* Phi   = (unsigned short*)(ws + OFF_GPART);          // after k_gred
  unsigned short* Plo   = (unsigned short*)(ws + OFF_GPART + 2097152);
  float*          Ef    = (float*)(ws + OFF_GPART + 4194304);
  unsigned short* othi  = xlo;    // O^T bf16, written K5 (after Ghi/Glo consumed)
  unsigned short* y1t   = xhi;    // y1^T bf16, written K6
  unsigned short* finT  = xthi;   // final^T bf16, written K7

  float* outF  = (float*)d_out;
  float* attnO = outF + 16777216;   // second output (attn)

  k_zero<<<dim3(16), dim3(256), 0, stream>>>(xsum);
  k_sigma<<<dim3(2), dim3(256), 0, stream>>>(W1, u1, W2, u2, sig);
  k_wconv<<<dim3(128), dim3(256), 0, stream>>>(W1, W2, sig, W1s, W2s);
  k_convert<<<dim3(64,4,16), dim3(256), 0, stream>>>(x, xhi, xlo, xthi, xsum);
  k_gram<<<dim3(4,4,16), dim3(256), 0, stream>>>(xhi, xlo, G0, Gp);
  k_gred<<<dim3(1024), dim3(256), 0, stream>>>(G0, Gp, Ghi, Glo);
  k_qg<<<dim3(2,2,16), dim3(256), 0, stream>>>(Wq, Ghi, Glo, Phi, Plo);
  k_e<<<dim3(2,2,16), dim3(256), 0, stream>>>(Phi, Plo, Wk, Ef);
  k_soft<<<dim3(128), dim3(256), 0, stream>>>(Ef, Wq, bq, Wk, bk, Wv, bv,
                                              gamma, xsum, Mw, rowadd, attnO);
  k_gemm<0><<<dim3(32,2,16), dim3(256), 0, stream>>>(xthi, Mw, othi, rowadd, b1, beta, othi);
  k_gemm<1><<<dim3(32,2,16), dim3(256), 0, stream>>>(othi, W1s, othi, rowadd, b1, beta, y1t);
  k_gemm<2><<<dim3(32,2,16), dim3(256), 0, stream>>>(y1t, W2s, othi, rowadd, b2, beta, finT);
  k_tpose<<<dim3(64,4,16), dim3(256), 0, stream>>>(finT, outF);
}